// Round 3
// baseline (18533.469 us; speedup 1.0000x reference)
//
#include <hip/hip_runtime.h>
#include <math.h>

#define NI 64
#define NO 64
#define NH 512
#define NM 64
#define NN 128
#define NB 32
#define NS 256
#define ZD 2048
#define PD 268
#define GBLK 128
#define TPB 512
#define UPB 4          // hidden units per block (128*4 = 512)
#define STRIDE 36      // padded LDS stride for inT (16B-aligned rows, bank-spread)

__device__ __forceinline__ float sigm(float x){ return 1.0f/(1.0f+expf(-x)); }
__device__ __forceinline__ float softplus_(float x){ return (x>15.f)? x : log1pf(expf(x)); }

// ---- hand-rolled grid barrier: 8 groups x 16 blocks, monotonic counters ----
// bar[0]=top_gen, bar[32]=top_cnt, bar[64+g*32]=grp_cnt[g]; all zeroed per launch.
__device__ __forceinline__ void gbar(int* bar, int bid, int era) {
  __syncthreads();                       // all threads' stores drained (vmcnt at barrier)
  if (threadIdx.x == 0) {
    __threadfence();                     // release: wb L2 so peers see our global writes
    int* grp  = bar + 64 + (bid >> 4) * 32;
    int* topc = bar + 32;
    int* geng = bar;
    int pg = __hip_atomic_fetch_add(grp, 1, __ATOMIC_ACQ_REL, __HIP_MEMORY_SCOPE_AGENT);
    if (pg == era * 16 - 1) {            // last in group
      int pt = __hip_atomic_fetch_add(topc, 1, __ATOMIC_ACQ_REL, __HIP_MEMORY_SCOPE_AGENT);
      if (pt == era * 8 - 1)             // last group
        __hip_atomic_store(geng, era, __ATOMIC_RELEASE, __HIP_MEMORY_SCOPE_AGENT);
    }
    while (__hip_atomic_load(geng, __ATOMIC_RELAXED, __HIP_MEMORY_SCOPE_AGENT) < era)
      __builtin_amdgcn_s_sleep(1);
    __threadfence();                     // acquire: inv L1/L2 so we see peers' writes
  }
  __syncthreads();
}

struct P1S { float inT[64*STRIDE]; float zpart[4*16*32]; float zfull[16*32]; };
struct P3S { float h[NH]; float pp[544]; float p[PD];
             float rk[NM], wk[NM], e[NM], a[NM];
             float sim[NN]; float red[8*64]; float r[NM]; };
union  USH { P1S p1; P3S p3; };

// content+location addressing; 512 threads; mem_s XOR-swizzled:
// logical mem[n][m] at float offset n*64 + (m ^ ((n&7)<<2)).
__device__ void address_head(int t, const float* __restrict__ ks,
                             const float* __restrict__ scal,
                             float* __restrict__ w_arr,
                             const float* __restrict__ mem_s,
                             float* __restrict__ sim_s)
{
  {
    int n = t >> 2, sub = t & 3;
    int cn = (n & 7) << 2;
    float dot = 0.f, sq = 0.f;
#pragma unroll
    for (int i = 0; i < 16; i += 4) {
      int m = sub*16 + i;
      float4 mv = *(const float4*)&mem_s[n*NM + (m ^ cn)];
      float4 kv = *(const float4*)&ks[m];
      dot = fmaf(kv.x, mv.x, dot); dot = fmaf(kv.y, mv.y, dot);
      dot = fmaf(kv.z, mv.z, dot); dot = fmaf(kv.w, mv.w, dot);
      sq  = fmaf(mv.x, mv.x, sq);  sq  = fmaf(mv.y, mv.y, sq);
      sq  = fmaf(mv.z, mv.z, sq);  sq  = fmaf(mv.w, mv.w, sq);
    }
    dot += __shfl_xor(dot, 1); sq += __shfl_xor(sq, 1);
    dot += __shfl_xor(dot, 2); sq += __shfl_xor(sq, 2);
    if (sub == 0) sim_s[n] = dot / (scal[0]*sqrtf(sq) + 1e-8f);
  }
  __syncthreads();
  if (t < 64) {   // wave 0: softmax+gate+shift+sharpen; lane l owns rows l, l+64
    int l = t;
    float beta = scal[1], g = scal[2], s0 = scal[3], s1 = scal[4], s2 = scal[5], gamma = scal[6];
    float x0 = beta*sim_s[l], x1 = beta*sim_s[l+64];
    float mx = fmaxf(x0, x1);
#pragma unroll
    for (int off=32; off; off>>=1) mx = fmaxf(mx, __shfl_xor(mx, off));
    float e0 = expf(x0-mx), e1 = expf(x1-mx);
    float sm = e0+e1;
#pragma unroll
    for (int off=32; off; off>>=1) sm += __shfl_xor(sm, off);
    float inv = 1.0f/sm;
    float wg0 = g*e0*inv + (1.f-g)*w_arr[l];
    float wg1 = g*e1*inv + (1.f-g)*w_arr[l+64];
    float up0 = __shfl(wg0, (l+1)&63);
    float w1f = __shfl(wg1, 0);
    float plus0 = (l==63) ? w1f : up0;
    float dn0 = __shfl(wg0, (l-1)&63);
    float w1b = __shfl(wg1, 63);
    float minus0 = (l==0) ? w1b : dn0;
    float up1 = __shfl(wg1, (l+1)&63);
    float w0f = __shfl(wg0, 0);
    float plus1 = (l==63) ? w0f : up1;
    float dn1 = __shfl(wg1, (l-1)&63);
    float w0b = __shfl(wg0, 63);
    float minus1 = (l==0) ? w0b : dn1;
    float ws0 = s0*plus0 + s1*wg0 + s2*minus0;
    float ws1 = s0*plus1 + s1*wg1 + s2*minus1;
    float wp0 = powf(fmaxf(ws0, 1e-12f), gamma);
    float wp1 = powf(fmaxf(ws1, 1e-12f), gamma);
    float tot = wp0+wp1;
#pragma unroll
    for (int off=32; off; off>>=1) tot += __shfl_xor(tot, off);
    float invt = 1.0f/tot;
    w_arr[l]    = wp0*invt;
    w_arr[l+64] = wp1*invt;
  }
  __syncthreads();
}

extern "C" __global__ __launch_bounds__(TPB, 1)
void ntm_coop(const float* __restrict__ inputs, const float* __restrict__ W_lstm,
              const float* __restrict__ b_lstm, const float* __restrict__ W_int,
              const float* __restrict__ b_int, const float* __restrict__ W_out,
              const float* __restrict__ b_out, float* __restrict__ out,
              float* __restrict__ wsf)
{
  __shared__ float mem_s[NN*NM];          // 32 KB persistent memory (batch blocks)
  __shared__ float wr_s[NN], ww_s[NN];
  __shared__ float scal_s[14];
  __shared__ USH u;

  int* bar   = (int*)wsf;                 // 4 KB barrier region (memset 0 per launch)
  float* hT0 = wsf + 1024;                // [512][32]
  float* hT1 = hT0 + NH*NB;
  float* rT  = hT1 + NH*NB;               // [64][32]

  const int t   = threadIdx.x;
  const int bid = blockIdx.x;
  const bool isB = (bid < NB);
  const int b    = bid;                   // batch (only if isB)
  int era = 0;

  // P1 decode
  const int pb_  = t & 31;                // batch for GEMM
  const int gate = (t >> 5) & 3;          // 0..3
  const int kp   = t >> 7;                // k-part 0..3
  const int j0   = bid * UPB;

  // pointwise ownership (t<128): unit pj, batch pw
  const int pj = t >> 5;                  // 0..3 (valid when t<128)
  const int pw = t & 31;
  float c_reg = 0.f;

  if (isB) {
    for (int i = t; i < NN*NM; i += TPB) mem_s[i] = 0.01f;
    if (t < NN) { wr_s[t] = (t==0)?1.f:0.f; ww_s[t] = (t==0)?1.f:0.f; }
  }
  __syncthreads();

  for (int step = 0; step < NS; ++step) {
    const int cur = step & 1;
    float* hT_cur = cur ? hT1 : hT0;
    const float* hT_prev = cur ? hT0 : hT1;

    // ============ P1: 16 LSTM columns x 32 batches, k in 10 chunks ============
    float acc0=0.f, acc1=0.f, acc2=0.f, acc3=0.f;
    for (int ch = 0; ch < 10; ++ch) {
      // stage chunk [64 k][32 b] into inT (stride 36)
      if (ch == 0) {                       // x_t (transpose on the fly)
        int sb = t >> 4, k4 = (t & 15) * 4;
        float4 v = *(const float4*)(inputs + (size_t)sb*NS*NI + (size_t)step*NI + k4);
        u.p1.inT[(k4+0)*STRIDE + sb] = v.x;
        u.p1.inT[(k4+1)*STRIDE + sb] = v.y;
        u.p1.inT[(k4+2)*STRIDE + sb] = v.z;
        u.p1.inT[(k4+3)*STRIDE + sb] = v.w;
      } else {
        int kr = t >> 3, b4 = (t & 7) * 4;
        float4 v;
        if (ch == 1) v = (step == 0) ? make_float4(0.01f,0.01f,0.01f,0.01f)
                                     : *(const float4*)(rT + kr*32 + b4);
        else         v = (step == 0) ? make_float4(0.f,0.f,0.f,0.f)
                                     : *(const float4*)(hT_prev + ((ch-2)*64 + kr)*32 + b4);
        *(float4*)&u.p1.inT[kr*STRIDE + b4] = v;
      }
      __syncthreads();
      const float* Wp = W_lstm + (size_t)(ch*64 + kp*16)*ZD + gate*NH + j0;
      const float* xp = &u.p1.inT[(kp*16)*STRIDE + pb_];
#pragma unroll
      for (int kk = 0; kk < 16; ++kk) {
        float xv = xp[kk*STRIDE];
        float4 w = *(const float4*)(Wp + (size_t)kk*ZD);
        acc0 = fmaf(xv, w.x, acc0);
        acc1 = fmaf(xv, w.y, acc1);
        acc2 = fmaf(xv, w.z, acc2);
        acc3 = fmaf(xv, w.w, acc3);
      }
      __syncthreads();
    }
    {
      int base = (kp*16 + gate*4)*32 + pb_;
      u.p1.zpart[base]        = acc0;
      u.p1.zpart[base + 32]   = acc1;
      u.p1.zpart[base + 64]   = acc2;
      u.p1.zpart[base + 96]   = acc3;
    }
    __syncthreads();
    {  // reduce k-parts: col16 = t>>5, b = t&31
      int col16 = t >> 5, bb = t & 31;
      float z = u.p1.zpart[col16*32 + bb] + u.p1.zpart[(16+col16)*32 + bb]
              + u.p1.zpart[(32+col16)*32 + bb] + u.p1.zpart[(48+col16)*32 + bb]
              + b_lstm[(col16>>2)*NH + j0 + (col16&3)];
      u.p1.zfull[col16*32 + bb] = z;
    }
    __syncthreads();
    if (t < 128) {  // LSTM pointwise, c in register
      float zi = u.p1.zfull[(0*4+pj)*32 + pw];
      float zf = u.p1.zfull[(1*4+pj)*32 + pw];
      float zg = u.p1.zfull[(2*4+pj)*32 + pw];
      float zo = u.p1.zfull[(3*4+pj)*32 + pw];
      float cn = sigm(zf)*c_reg + sigm(zi)*tanhf(zg);
      c_reg = cn;
      hT_cur[(j0+pj)*32 + pw] = sigm(zo)*tanhf(cn);
    }

    gbar(bar, bid, ++era);

    // ============ P3: per-batch NTM chain (blocks 0..31) ============
    if (isB) {
      u.p3.h[t] = hT_cur[t*32 + b];
      __syncthreads();
      // p = h @ W_int + b_int, k split in halves (536 tasks)
      {
        int c = t >> 1, half = t & 1;
        const float* Wc = W_int + (size_t)(half*256)*PD + c;
        const float* hh = u.p3.h + half*256;
        float pacc = 0.f;
#pragma unroll 8
        for (int k = 0; k < 256; ++k) pacc = fmaf(hh[k], Wc[(size_t)k*PD], pacc);
        u.p3.pp[t] = pacc;
        if (t < 24) {
          int id = 512 + t; int c2 = id >> 1; int h2 = id & 1;
          const float* Wc2 = W_int + (size_t)(h2*256)*PD + c2;
          const float* hh2 = u.p3.h + h2*256;
          float pa2 = 0.f;
#pragma unroll 8
          for (int k = 0; k < 256; ++k) pa2 = fmaf(hh2[k], Wc2[(size_t)k*PD], pa2);
          u.p3.pp[id] = pa2;
        }
      }
      __syncthreads();
      if (t < PD) u.p3.p[t] = u.p3.pp[2*t] + u.p3.pp[2*t+1] + b_int[t];
      __syncthreads();
      // head params
      if (t < NM) {
        float rk = tanhf(u.p3.p[t]);
        float wk = tanhf(u.p3.p[70+t]);
        u.p3.rk[t] = rk; u.p3.wk[t] = wk;
        u.p3.e[t] = sigm(u.p3.p[140+t]);
        u.p3.a[t] = tanhf(u.p3.p[204+t]);
        float sr = rk*rk, sw = wk*wk;
#pragma unroll
        for (int off=32; off; off>>=1){ sr += __shfl_xor(sr,off); sw += __shfl_xor(sw,off); }
        if (t == 0) { scal_s[0] = sqrtf(sr); scal_s[7] = sqrtf(sw); }
      }
      if (t == 64) {
        scal_s[1] = softplus_(u.p3.p[64]);
        scal_s[2] = sigm(u.p3.p[65]);
        float a0=u.p3.p[66], a1=u.p3.p[67], a2=u.p3.p[68];
        float m = fmaxf(a0,fmaxf(a1,a2));
        float e0=expf(a0-m), e1=expf(a1-m), e2=expf(a2-m);
        float s = e0+e1+e2;
        scal_s[3]=e0/s; scal_s[4]=e1/s; scal_s[5]=e2/s;
        scal_s[6] = 1.f + softplus_(u.p3.p[69]);
      }
      if (t == 128) {
        scal_s[8]  = softplus_(u.p3.p[134]);
        scal_s[9]  = sigm(u.p3.p[135]);
        float a0=u.p3.p[136], a1=u.p3.p[137], a2=u.p3.p[138];
        float m = fmaxf(a0,fmaxf(a1,a2));
        float e0=expf(a0-m), e1=expf(a1-m), e2=expf(a2-m);
        float s = e0+e1+e2;
        scal_s[10]=e0/s; scal_s[11]=e1/s; scal_s[12]=e2/s;
        scal_s[13] = 1.f + softplus_(u.p3.p[139]);
      }
      __syncthreads();

      // write addressing (old memory)
      address_head(t, u.p3.wk, &scal_s[7], ww_s, mem_s, u.p3.sim);

      // erase + add
      {
        int n = t >> 2, sub = t & 3;
        int cn = (n & 7) << 2;
        float w = ww_s[n];
#pragma unroll
        for (int i = 0; i < 16; i += 4) {
          int m = sub*16 + i;
          float* mp = &mem_s[n*NM + (m ^ cn)];
          float4 mv = *(float4*)mp;
          float4 ev = *(const float4*)&u.p3.e[m];
          float4 av = *(const float4*)&u.p3.a[m];
          mv.x = mv.x*(1.f - w*ev.x) + w*av.x;
          mv.y = mv.y*(1.f - w*ev.y) + w*av.y;
          mv.z = mv.z*(1.f - w*ev.z) + w*av.z;
          mv.w = mv.w*(1.f - w*ev.w) + w*av.w;
          *(float4*)mp = mv;
        }
      }
      __syncthreads();

      // read addressing (updated memory)
      address_head(t, u.p3.rk, &scal_s[0], wr_s, mem_s, u.p3.sim);

      // r = w_r @ mem
      {
        int part = t >> 6, m = t & 63;
        float racc = 0.f;
#pragma unroll
        for (int nn = 0; nn < 16; ++nn) {
          int n = part*16 + nn;
          racc = fmaf(wr_s[n], mem_s[n*NM + (m ^ ((n&7)<<2))], racc);
        }
        u.p3.red[part*64 + m] = racc;
      }
      __syncthreads();
      if (t < NM) {
        float rv = 0.f;
#pragma unroll
        for (int pq = 0; pq < 8; ++pq) rv += u.p3.red[pq*64 + t];
        u.p3.r[t] = rv;
        rT[t*32 + b] = rv;
      }
      __syncthreads();

      // out = [h, r] @ W_out + b_out
      {
        int part = t >> 6, c = t & 63;
        float oacc = 0.f;
        int k0 = part*72;
#pragma unroll 8
        for (int kk = 0; kk < 72; ++kk) {
          int k = k0 + kk;
          float v = (k < NH) ? u.p3.h[k] : u.p3.r[k-NH];
          oacc = fmaf(v, W_out[(size_t)k*NO + c], oacc);
        }
        u.p3.red[part*64 + c] = oacc;
      }
      __syncthreads();
      if (t < NO) {
        float ov = b_out[t];
#pragma unroll
        for (int pq = 0; pq < 8; ++pq) ov += u.p3.red[pq*64 + t];
        out[(size_t)b*NS*NO + (size_t)step*NO + t] = ov;
      }
    }

    gbar(bar, bid, ++era);
  }
}

extern "C" void kernel_launch(void* const* d_in, const int* in_sizes, int n_in,
                              void* d_out, int out_size, void* d_ws, size_t ws_size,
                              hipStream_t stream) {
  const float* inputs = (const float*)d_in[0];
  const float* W_lstm = (const float*)d_in[1];
  const float* b_lstm = (const float*)d_in[2];
  const float* W_int  = (const float*)d_in[3];
  const float* b_int  = (const float*)d_in[4];
  const float* W_out  = (const float*)d_in[5];
  const float* b_out  = (const float*)d_in[6];
  float* outp = (float*)d_out;
  float* wsp  = (float*)d_ws;

  hipMemsetAsync(d_ws, 0, 4096, stream);   // zero barrier counters every call

  void* args[] = { (void*)&inputs, (void*)&W_lstm, (void*)&b_lstm,
                   (void*)&W_int, (void*)&b_int, (void*)&W_out, (void*)&b_out,
                   (void*)&outp, (void*)&wsp };
  hipLaunchCooperativeKernel((const void*)ntm_coop, dim3(GBLK), dim3(TPB),
                             args, 0, stream);
}

// Round 4
// 11595.467 us; speedup vs baseline: 1.5983x; 1.5983x over previous
//
#include <hip/hip_runtime.h>
#include <math.h>

#define NI 64
#define NO 64
#define NH 512
#define NM 64
#define NN 128
#define NB 32
#define NS 256
#define ZD 2048
#define PD 268
#define GBLK 128
#define TPB 512
#define UPB 4          // hidden units per block (128*4 = 512)
#define ST2 648        // LDS stride for inT rows [b][k]

__device__ __forceinline__ float sigm(float x){ return 1.0f/(1.0f+expf(-x)); }
__device__ __forceinline__ float softplus_(float x){ return (x>15.f)? x : log1pf(expf(x)); }

// ---- coherent (cross-XCD) access helpers: relaxed system-scope = sc0 sc1, no fences ----
__device__ __forceinline__ float cloadf(const float* p){
  return __hip_atomic_load(p, __ATOMIC_RELAXED, __HIP_MEMORY_SCOPE_SYSTEM);
}
__device__ __forceinline__ void cstoref(float* p, float v){
  __hip_atomic_store(p, v, __ATOMIC_RELAXED, __HIP_MEMORY_SCOPE_SYSTEM);
}
__device__ __forceinline__ float2 cloadf2(const float* p){
  unsigned long long u = __hip_atomic_load((const unsigned long long*)p,
                                           __ATOMIC_RELAXED, __HIP_MEMORY_SCOPE_SYSTEM);
  return __builtin_bit_cast(float2, u);
}
__device__ __forceinline__ int cloadi(const int* p){
  return __hip_atomic_load(p, __ATOMIC_RELAXED, __HIP_MEMORY_SCOPE_SYSTEM);
}
__device__ __forceinline__ void cstorei(int* p, int v){
  __hip_atomic_store(p, v, __ATOMIC_RELAXED, __HIP_MEMORY_SCOPE_SYSTEM);
}

// ---- fence-free grid barrier: per-block flag words (128B apart), wave0 polls all ----
__device__ __forceinline__ void gbar(int* flags, int bid, int era){
  __syncthreads();                       // drains every wave's vmem stores (vmcnt0 before s_barrier)
  if (threadIdx.x == 0)
    cstorei(&flags[bid*32], era);
  if (threadIdx.x < 64) {
    const int i0 = (int)threadIdx.x * 2, i1 = i0 + 1;
    for (;;) {
      int a = cloadi(&flags[i0*32]);
      int c = cloadi(&flags[i1*32]);
      if (a >= era && c >= era) break;
      __builtin_amdgcn_s_sleep(2);
    }
  }
  __syncthreads();
}

struct P1S { float inT[NB*ST2]; float zpart[4*16*32]; float zfull[16*32]; };
struct P3S { float h[NH]; float pp[544]; float p[PD];
             float rk[NM], wk[NM], e[NM], a[NM];
             float sim[NN]; float red[8*64]; float r[NM]; };
union  USH { P1S p1; P3S p3; };

// content+location addressing; 512 threads; mem_s XOR-swizzled:
// logical mem[n][m] at float offset n*64 + (m ^ ((n&7)<<2)).
__device__ void address_head(int t, const float* __restrict__ ks,
                             const float* __restrict__ scal,
                             float* __restrict__ w_arr,
                             const float* __restrict__ mem_s,
                             float* __restrict__ sim_s)
{
  {
    int n = t >> 2, sub = t & 3;
    int cn = (n & 7) << 2;
    float dot = 0.f, sq = 0.f;
#pragma unroll
    for (int i = 0; i < 16; i += 4) {
      int m = sub*16 + i;
      float4 mv = *(const float4*)&mem_s[n*NM + (m ^ cn)];
      float4 kv = *(const float4*)&ks[m];
      dot = fmaf(kv.x, mv.x, dot); dot = fmaf(kv.y, mv.y, dot);
      dot = fmaf(kv.z, mv.z, dot); dot = fmaf(kv.w, mv.w, dot);
      sq  = fmaf(mv.x, mv.x, sq);  sq  = fmaf(mv.y, mv.y, sq);
      sq  = fmaf(mv.z, mv.z, sq);  sq  = fmaf(mv.w, mv.w, sq);
    }
    dot += __shfl_xor(dot, 1); sq += __shfl_xor(sq, 1);
    dot += __shfl_xor(dot, 2); sq += __shfl_xor(sq, 2);
    if (sub == 0) sim_s[n] = dot / (scal[0]*sqrtf(sq) + 1e-8f);
  }
  __syncthreads();
  if (t < 64) {   // wave 0: softmax+gate+shift+sharpen; lane l owns rows l, l+64
    int l = t;
    float beta = scal[1], g = scal[2], s0 = scal[3], s1 = scal[4], s2 = scal[5], gamma = scal[6];
    float x0 = beta*sim_s[l], x1 = beta*sim_s[l+64];
    float mx = fmaxf(x0, x1);
#pragma unroll
    for (int off=32; off; off>>=1) mx = fmaxf(mx, __shfl_xor(mx, off));
    float e0 = expf(x0-mx), e1 = expf(x1-mx);
    float sm = e0+e1;
#pragma unroll
    for (int off=32; off; off>>=1) sm += __shfl_xor(sm, off);
    float inv = 1.0f/sm;
    float wg0 = g*e0*inv + (1.f-g)*w_arr[l];
    float wg1 = g*e1*inv + (1.f-g)*w_arr[l+64];
    float up0 = __shfl(wg0, (l+1)&63);
    float w1f = __shfl(wg1, 0);
    float plus0 = (l==63) ? w1f : up0;
    float dn0 = __shfl(wg0, (l-1)&63);
    float w1b = __shfl(wg1, 63);
    float minus0 = (l==0) ? w1b : dn0;
    float up1 = __shfl(wg1, (l+1)&63);
    float w0f = __shfl(wg0, 0);
    float plus1 = (l==63) ? w0f : up1;
    float dn1 = __shfl(wg1, (l-1)&63);
    float w0b = __shfl(wg0, 63);
    float minus1 = (l==0) ? w0b : dn1;
    float ws0 = s0*plus0 + s1*wg0 + s2*minus0;
    float ws1 = s0*plus1 + s1*wg1 + s2*minus1;
    float wp0 = powf(fmaxf(ws0, 1e-12f), gamma);
    float wp1 = powf(fmaxf(ws1, 1e-12f), gamma);
    float tot = wp0+wp1;
#pragma unroll
    for (int off=32; off; off>>=1) tot += __shfl_xor(tot, off);
    float invt = 1.0f/tot;
    w_arr[l]    = wp0*invt;
    w_arr[l+64] = wp1*invt;
  }
  __syncthreads();
}

extern "C" __global__ __launch_bounds__(TPB, 1)
void ntm_coop(const float* __restrict__ inputs, const float* __restrict__ W_lstm,
              const float* __restrict__ b_lstm, const float* __restrict__ W_int,
              const float* __restrict__ b_int, const float* __restrict__ W_out,
              const float* __restrict__ b_out, float* __restrict__ out,
              float* __restrict__ wsf)
{
  __shared__ float mem_s[NN*NM];          // 32 KB persistent memory (batch blocks)
  __shared__ float wr_s[NN], ww_s[NN];
  __shared__ float scal_s[14];
  __shared__ USH u;

  int*   flags = (int*)wsf;               // 128 flags, 32-int stride (16 KB, memset 0/launch)
  float* hT0   = wsf + 4096;              // [batch][unit] 512*32
  float* hT1   = hT0 + NH*NB;
  float* rT    = hT1 + NH*NB;             // [batch][m] 32*64

  const int t   = threadIdx.x;
  const int bid = blockIdx.x;
  const bool isB = (bid < NB);
  const int b    = bid;
  int era = 0;

  // P1 GEMM decode: 4 k-parts x 4 gates x 32 batches
  const int pb_  = t & 31;
  const int gate = (t >> 5) & 3;
  const int kp   = t >> 7;                // 0..3, k-slice of 160
  const int j0   = bid * UPB;

  // pointwise ownership (t<128): unit pj (0..3), batch pw
  const int pj = t >> 5;
  const int pw = t & 31;
  float c_reg = 0.f;

  if (isB) {
    for (int i = t; i < NN*NM; i += TPB) mem_s[i] = 0.01f;
    if (t < NN) { wr_s[t] = (t==0)?1.f:0.f; ww_s[t] = (t==0)?1.f:0.f; }
  }
  __syncthreads();

  for (int step = 0; step < NS; ++step) {
    float* hTW = (step & 1) ? hT1 : hT0;       // written this step
    const float* hTP = (step & 1) ? hT0 : hT1; // previous step's h

    // ============ P1 staging: inT[b][0:64]=x, [64:128]=r, [128:640]=h ============
    {
      int sb = t >> 4, k4 = (t & 15) * 4;
      float4 xv = *(const float4*)(inputs + ((size_t)sb*NS + step)*NI + k4);
      *(float4*)&u.p1.inT[sb*ST2 + k4] = xv;
    }
    if (step == 0) {
#pragma unroll
      for (int i = 0; i < 2; ++i) {       // r0 = 0.01
        int g2 = t + 512*i; int b_ = g2 >> 5, off2 = (g2 & 31) * 2;
        *(float2*)&u.p1.inT[b_*ST2 + 64 + off2] = make_float2(0.01f, 0.01f);
      }
#pragma unroll
      for (int i = 0; i < 16; ++i) {      // h0 = 0
        int g2 = t + 512*i; int b_ = g2 >> 8, off2 = (g2 & 255) * 2;
        *(float2*)&u.p1.inT[b_*ST2 + 128 + off2] = make_float2(0.f, 0.f);
      }
    } else {
#pragma unroll
      for (int i = 0; i < 2; ++i) {       // rT coherent, coalesced f2
        int g2 = t + 512*i; int b_ = g2 >> 5, off2 = (g2 & 31) * 2;
        float2 v = cloadf2(rT + 2*g2);
        *(float2*)&u.p1.inT[b_*ST2 + 64 + off2] = v;
      }
#pragma unroll
      for (int i = 0; i < 16; ++i) {      // hT coherent, coalesced f2
        int g2 = t + 512*i; int b_ = g2 >> 8, off2 = (g2 & 255) * 2;
        float2 v = cloadf2(hTP + 2*g2);
        *(float2*)&u.p1.inT[b_*ST2 + 128 + off2] = v;
      }
    }
    __syncthreads();

    // ============ P1 GEMM: 16 cols x 32 batches, k-slice per kp ============
    {
      float a0=0.f, a1=0.f, a2=0.f, a3=0.f;
      const float* xrow = &u.p1.inT[pb_*ST2 + kp*160];
      const float* Wp = W_lstm + (size_t)(kp*160)*ZD + gate*NH + j0;
#pragma unroll 4
      for (int k4 = 0; k4 < 160; k4 += 4) {
        float4 x = *(const float4*)&xrow[k4];
        float4 w0 = *(const float4*)(Wp + (size_t)(k4+0)*ZD);
        float4 w1 = *(const float4*)(Wp + (size_t)(k4+1)*ZD);
        float4 w2 = *(const float4*)(Wp + (size_t)(k4+2)*ZD);
        float4 w3 = *(const float4*)(Wp + (size_t)(k4+3)*ZD);
        a0 = fmaf(x.x, w0.x, a0); a1 = fmaf(x.x, w0.y, a1);
        a2 = fmaf(x.x, w0.z, a2); a3 = fmaf(x.x, w0.w, a3);
        a0 = fmaf(x.y, w1.x, a0); a1 = fmaf(x.y, w1.y, a1);
        a2 = fmaf(x.y, w1.z, a2); a3 = fmaf(x.y, w1.w, a3);
        a0 = fmaf(x.z, w2.x, a0); a1 = fmaf(x.z, w2.y, a1);
        a2 = fmaf(x.z, w2.z, a2); a3 = fmaf(x.z, w2.w, a3);
        a0 = fmaf(x.w, w3.x, a0); a1 = fmaf(x.w, w3.y, a1);
        a2 = fmaf(x.w, w3.z, a2); a3 = fmaf(x.w, w3.w, a3);
      }
      int base = (kp*16 + gate*4)*32 + pb_;
      u.p1.zpart[base]      = a0;
      u.p1.zpart[base+32]   = a1;
      u.p1.zpart[base+64]   = a2;
      u.p1.zpart[base+96]   = a3;
    }
    __syncthreads();
    {  // reduce k-parts + bias
      int col16 = t >> 5, bb = t & 31;
      float z = u.p1.zpart[col16*32 + bb] + u.p1.zpart[(16+col16)*32 + bb]
              + u.p1.zpart[(32+col16)*32 + bb] + u.p1.zpart[(48+col16)*32 + bb]
              + b_lstm[(col16>>2)*NH + j0 + (col16&3)];
      u.p1.zfull[col16*32 + bb] = z;
    }
    __syncthreads();
    if (t < 128) {  // LSTM pointwise; h -> coherent [batch][unit]
      float zi = u.p1.zfull[(0*4+pj)*32 + pw];
      float zf = u.p1.zfull[(1*4+pj)*32 + pw];
      float zg = u.p1.zfull[(2*4+pj)*32 + pw];
      float zo = u.p1.zfull[(3*4+pj)*32 + pw];
      float cn = sigm(zf)*c_reg + sigm(zi)*tanhf(zg);
      c_reg = cn;
      cstoref(&hTW[pw*NH + (j0+pj)], sigm(zo)*tanhf(cn));
    }

    gbar(flags, bid, ++era);

    // ============ P3: per-batch NTM chain (blocks 0..31) ============
    if (isB) {
      u.p3.h[t] = cloadf(&hTW[b*NH + t]);      // coalesced coherent
      __syncthreads();
      // p = h @ W_int + b_int, k split in halves (536 tasks)
      {
        int c = t >> 1, half = t & 1;
        const float* Wc = W_int + (size_t)(half*256)*PD + c;
        const float* hh = u.p3.h + half*256;
        float pacc = 0.f;
#pragma unroll 8
        for (int k = 0; k < 256; ++k) pacc = fmaf(hh[k], Wc[(size_t)k*PD], pacc);
        u.p3.pp[t] = pacc;
        if (t < 24) {
          int id = 512 + t; int c2 = id >> 1; int h2 = id & 1;
          const float* Wc2 = W_int + (size_t)(h2*256)*PD + c2;
          const float* hh2 = u.p3.h + h2*256;
          float pa2 = 0.f;
#pragma unroll 8
          for (int k = 0; k < 256; ++k) pa2 = fmaf(hh2[k], Wc2[(size_t)k*PD], pa2);
          u.p3.pp[id] = pa2;
        }
      }
      __syncthreads();
      if (t < PD) u.p3.p[t] = u.p3.pp[2*t] + u.p3.pp[2*t+1] + b_int[t];
      __syncthreads();
      // head params
      if (t < NM) {
        float rk = tanhf(u.p3.p[t]);
        float wk = tanhf(u.p3.p[70+t]);
        u.p3.rk[t] = rk; u.p3.wk[t] = wk;
        u.p3.e[t] = sigm(u.p3.p[140+t]);
        u.p3.a[t] = tanhf(u.p3.p[204+t]);
        float sr = rk*rk, sw = wk*wk;
#pragma unroll
        for (int off=32; off; off>>=1){ sr += __shfl_xor(sr,off); sw += __shfl_xor(sw,off); }
        if (t == 0) { scal_s[0] = sqrtf(sr); scal_s[7] = sqrtf(sw); }
      }
      if (t == 64) {
        scal_s[1] = softplus_(u.p3.p[64]);
        scal_s[2] = sigm(u.p3.p[65]);
        float a0=u.p3.p[66], a1=u.p3.p[67], a2=u.p3.p[68];
        float m = fmaxf(a0,fmaxf(a1,a2));
        float e0=expf(a0-m), e1=expf(a1-m), e2=expf(a2-m);
        float s = e0+e1+e2;
        scal_s[3]=e0/s; scal_s[4]=e1/s; scal_s[5]=e2/s;
        scal_s[6] = 1.f + softplus_(u.p3.p[69]);
      }
      if (t == 128) {
        scal_s[8]  = softplus_(u.p3.p[134]);
        scal_s[9]  = sigm(u.p3.p[135]);
        float a0=u.p3.p[136], a1=u.p3.p[137], a2=u.p3.p[138];
        float m = fmaxf(a0,fmaxf(a1,a2));
        float e0=expf(a0-m), e1=expf(a1-m), e2=expf(a2-m);
        float s = e0+e1+e2;
        scal_s[10]=e0/s; scal_s[11]=e1/s; scal_s[12]=e2/s;
        scal_s[13] = 1.f + softplus_(u.p3.p[139]);
      }
      __syncthreads();

      address_head(t, u.p3.wk, &scal_s[7], ww_s, mem_s, u.p3.sim);

      {  // erase + add
        int n = t >> 2, sub = t & 3;
        int cn = (n & 7) << 2;
        float w = ww_s[n];
#pragma unroll
        for (int i = 0; i < 16; i += 4) {
          int m = sub*16 + i;
          float* mp = &mem_s[n*NM + (m ^ cn)];
          float4 mv = *(float4*)mp;
          float4 ev = *(const float4*)&u.p3.e[m];
          float4 av = *(const float4*)&u.p3.a[m];
          mv.x = mv.x*(1.f - w*ev.x) + w*av.x;
          mv.y = mv.y*(1.f - w*ev.y) + w*av.y;
          mv.z = mv.z*(1.f - w*ev.z) + w*av.z;
          mv.w = mv.w*(1.f - w*ev.w) + w*av.w;
          *(float4*)mp = mv;
        }
      }
      __syncthreads();

      address_head(t, u.p3.rk, &scal_s[0], wr_s, mem_s, u.p3.sim);

      {  // r = w_r @ mem
        int part = t >> 6, m = t & 63;
        float racc = 0.f;
#pragma unroll
        for (int nn = 0; nn < 16; ++nn) {
          int n = part*16 + nn;
          racc = fmaf(wr_s[n], mem_s[n*NM + (m ^ ((n&7)<<2))], racc);
        }
        u.p3.red[part*64 + m] = racc;
      }
      __syncthreads();
      if (t < NM) {
        float rv = 0.f;
#pragma unroll
        for (int pq = 0; pq < 8; ++pq) rv += u.p3.red[pq*64 + t];
        u.p3.r[t] = rv;
        cstoref(&rT[b*NM + t], rv);
      }
      __syncthreads();

      {  // out = [h, r] @ W_out + b_out
        int part = t >> 6, c = t & 63;
        float oacc = 0.f;
        int k0 = part*72;
#pragma unroll 8
        for (int kk = 0; kk < 72; ++kk) {
          int k = k0 + kk;
          float v = (k < NH) ? u.p3.h[k] : u.p3.r[k-NH];
          oacc = fmaf(v, W_out[(size_t)k*NO + c], oacc);
        }
        u.p3.red[part*64 + c] = oacc;
      }
      __syncthreads();
      if (t < NO) {
        float ov = b_out[t];
#pragma unroll
        for (int pq = 0; pq < 8; ++pq) ov += u.p3.red[pq*64 + t];
        out[(size_t)b*NS*NO + (size_t)step*NO + t] = ov;
      }
    }

    gbar(flags, bid, ++era);
  }
}

extern "C" void kernel_launch(void* const* d_in, const int* in_sizes, int n_in,
                              void* d_out, int out_size, void* d_ws, size_t ws_size,
                              hipStream_t stream) {
  const float* inputs = (const float*)d_in[0];
  const float* W_lstm = (const float*)d_in[1];
  const float* b_lstm = (const float*)d_in[2];
  const float* W_int  = (const float*)d_in[3];
  const float* b_int  = (const float*)d_in[4];
  const float* W_out  = (const float*)d_in[5];
  const float* b_out  = (const float*)d_in[6];
  float* outp = (float*)d_out;
  float* wsp  = (float*)d_ws;

  hipMemsetAsync(d_ws, 0, 4096 * sizeof(int), stream);  // zero barrier flags per launch

  void* args[] = { (void*)&inputs, (void*)&W_lstm, (void*)&b_lstm,
                   (void*)&W_int, (void*)&b_int, (void*)&W_out, (void*)&b_out,
                   (void*)&outp, (void*)&wsp };
  hipLaunchCooperativeKernel((const void*)ntm_coop, dim3(GBLK), dim3(TPB),
                             args, 0, stream);
}